// Round 1
// baseline (426.317 us; speedup 1.0000x reference)
//
#include <hip/hip_runtime.h>
#include <math.h>

// Problem constants: activations [N=8, C=64, D=32, H=64, W=64] fp32,
// blocks of blk=16 along C, mantissa=7.
#define CH_STRIDE 131072   // D*H*W = 32*64*64 (elements)
#define SPATIAL4  32768    // CH_STRIDE / 4 (float4 groups per (n,c) plane)
#define NBLK      32       // N * (C/16) = 8 * 4
#define BLK       16       // channels per BFP block

// One thread = one float4 group (4 spatial sites) x 16 channels.
// Consecutive lanes -> consecutive 16B addresses at every channel step:
// fully coalesced, 16 B/lane.
__global__ __launch_bounds__(256)
void bfp_quant_kernel(const float* __restrict__ in, float* __restrict__ out) {
    const int tid = blockIdx.x * blockDim.x + threadIdx.x;   // 0 .. NBLK*SPATIAL4-1
    const int sp4 = tid & (SPATIAL4 - 1);                    // spatial float4 index
    const int nb  = tid >> 15;                               // (n*4 + block) in [0,32)

    // element base = nb * (16 channels * CH_STRIDE) + sp4*4
    const long base = (long)nb * (long)(BLK * CH_STRIDE) + (long)sp4 * 4;
    const float4* __restrict__ ip = (const float4*)(in  + base);
    float4*       __restrict__ op = (float4*)(out + base);

    float v[BLK][4];
    float mx0 = 0.f, mx1 = 0.f, mx2 = 0.f, mx3 = 0.f;

    #pragma unroll
    for (int c = 0; c < BLK; ++c) {
        float4 t = ip[c * SPATIAL4];
        v[c][0] = t.x; v[c][1] = t.y; v[c][2] = t.z; v[c][3] = t.w;
        mx0 = fmaxf(mx0, fabsf(t.x));
        mx1 = fmaxf(mx1, fabsf(t.y));
        mx2 = fmaxf(mx2, fabsf(t.z));
        mx3 = fmaxf(mx3, fabsf(t.w));
    }

    // shared_exp = e-1 where frexp(max_abs) -> f*2^e ; quantum = 2^(shared_exp-6) = 2^(e-7)
    int e0, e1, e2, e3;
    (void)frexpf(mx0, &e0); (void)frexpf(mx1, &e1);
    (void)frexpf(mx2, &e2); (void)frexpf(mx3, &e3);
    const float q0 = ldexpf(1.0f, e0 - 7), i0 = ldexpf(1.0f, 7 - e0);
    const float q1 = ldexpf(1.0f, e1 - 7), i1 = ldexpf(1.0f, 7 - e1);
    const float q2 = ldexpf(1.0f, e2 - 7), i2 = ldexpf(1.0f, 7 - e2);
    const float q3 = ldexpf(1.0f, e3 - 7), i3 = ldexpf(1.0f, 7 - e3);
    // max_abs == 0 needs no special case: all inputs 0 -> rint(0)*q = 0.

    const float lim = 127.0f;  // 2^mantissa - 1

    #pragma unroll
    for (int c = 0; c < BLK; ++c) {
        float4 r;
        r.x = fminf(fmaxf(rintf(v[c][0] * i0), -lim), lim) * q0;
        r.y = fminf(fmaxf(rintf(v[c][1] * i1), -lim), lim) * q1;
        r.z = fminf(fmaxf(rintf(v[c][2] * i2), -lim), lim) * q2;
        r.w = fminf(fmaxf(rintf(v[c][3] * i3), -lim), lim) * q3;
        op[c * SPATIAL4] = r;
    }
}

extern "C" void kernel_launch(void* const* d_in, const int* in_sizes, int n_in,
                              void* d_out, int out_size, void* d_ws, size_t ws_size,
                              hipStream_t stream) {
    const float* in  = (const float*)d_in[0];
    float*       out = (float*)d_out;
    // total threads = NBLK * SPATIAL4 = 32 * 32768 = 1,048,576
    const int threads = 256;
    const int blocks  = (NBLK * SPATIAL4) / threads;  // 4096
    bfp_quant_kernel<<<blocks, threads, 0, stream>>>(in, out);
}

// Round 2
// 426.111 us; speedup vs baseline: 1.0005x; 1.0005x over previous
//
#include <hip/hip_runtime.h>
#include <math.h>

// Problem: activations [N=8, C=64, D=32, H=64, W=64] fp32, BFP blocks of 16
// along C (stride D*H*W = 131072 elems = 512 KiB), mantissa = 7.
#define CH_STRIDE 131072   // D*H*W elements
#define SPATIAL4  32768    // CH_STRIDE / 4 (float4 groups per (n,c) plane)
#define BLK       16       // channels per BFP block

// Lane mapping inside a wave: sp = lane & 15 (spatial float4), ch2 = lane >> 4
// (channel quad). Each thread loads 4 channels (ch2*4 + j) of one float4 site;
// the 16-channel max is completed by a butterfly shuffle over lanes
// {sp, sp+16, sp+32, sp+48}. No LDS, no barrier, ~16 live data regs.
__global__ __launch_bounds__(256)
void bfp_quant_kernel(const float* __restrict__ in, float* __restrict__ out) {
    const int tid   = blockIdx.x * 256 + threadIdx.x;
    const int lane  = threadIdx.x & 63;
    const int sp    = lane & 15;
    const int ch2   = lane >> 4;
    const int wid   = tid >> 6;          // global wave id, 0..65535
    const int chunk = wid & 2047;        // sp4 chunk within plane (2048 = SPATIAL4/16)
    const int nb    = wid >> 11;         // (n*4 + channel_block), 0..31
    const int sp4   = (chunk << 4) + sp;

    const long base = (long)nb * (BLK * (long)CH_STRIDE)
                    + (long)(ch2 * 4) * CH_STRIDE
                    + (long)sp4 * 4;
    const float4* __restrict__ ip = (const float4*)(in  + base);
    float4*       __restrict__ op = (float4*)(out + base);

    const float4 v0 = ip[0];
    const float4 v1 = ip[SPATIAL4];
    const float4 v2 = ip[2 * SPATIAL4];
    const float4 v3 = ip[3 * SPATIAL4];

    // per-thread max over its 4 channels, per spatial component
    float mx = fmaxf(fmaxf(fabsf(v0.x), fabsf(v1.x)), fmaxf(fabsf(v2.x), fabsf(v3.x)));
    float my = fmaxf(fmaxf(fabsf(v0.y), fabsf(v1.y)), fmaxf(fabsf(v2.y), fabsf(v3.y)));
    float mz = fmaxf(fmaxf(fabsf(v0.z), fabsf(v1.z)), fmaxf(fabsf(v2.z), fabsf(v3.z)));
    float mw = fmaxf(fmaxf(fabsf(v0.w), fabsf(v1.w)), fmaxf(fabsf(v2.w), fabsf(v3.w)));

    // butterfly across the 4 channel-quads (lanes xor 16, xor 32)
    mx = fmaxf(mx, __shfl_xor(mx, 16, 64));
    my = fmaxf(my, __shfl_xor(my, 16, 64));
    mz = fmaxf(mz, __shfl_xor(mz, 16, 64));
    mw = fmaxf(mw, __shfl_xor(mw, 16, 64));
    mx = fmaxf(mx, __shfl_xor(mx, 32, 64));
    my = fmaxf(my, __shfl_xor(my, 32, 64));
    mz = fmaxf(mz, __shfl_xor(mz, 32, 64));
    mw = fmaxf(mw, __shfl_xor(mw, 32, 64));

    // shared_exp = e-1 (frexp: max = f*2^e, f in [0.5,1)); quantum = 2^(e-7)
    int ex, ey, ez, ew;
    (void)frexpf(mx, &ex); (void)frexpf(my, &ey);
    (void)frexpf(mz, &ez); (void)frexpf(mw, &ew);
    const float qx = ldexpf(1.0f, ex - 7), rx = ldexpf(1.0f, 7 - ex);
    const float qy = ldexpf(1.0f, ey - 7), ry = ldexpf(1.0f, 7 - ey);
    const float qz = ldexpf(1.0f, ez - 7), rz = ldexpf(1.0f, 7 - ez);
    const float qw = ldexpf(1.0f, ew - 7), rw = ldexpf(1.0f, 7 - ew);
    const float lim = 127.0f;   // 2^mantissa - 1; max==0 case falls out (rint(0)=0)

    float4 o;
    o.x = fminf(fmaxf(rintf(v0.x * rx), -lim), lim) * qx;
    o.y = fminf(fmaxf(rintf(v0.y * ry), -lim), lim) * qy;
    o.z = fminf(fmaxf(rintf(v0.z * rz), -lim), lim) * qz;
    o.w = fminf(fmaxf(rintf(v0.w * rw), -lim), lim) * qw;
    op[0] = o;
    o.x = fminf(fmaxf(rintf(v1.x * rx), -lim), lim) * qx;
    o.y = fminf(fmaxf(rintf(v1.y * ry), -lim), lim) * qy;
    o.z = fminf(fmaxf(rintf(v1.z * rz), -lim), lim) * qz;
    o.w = fminf(fmaxf(rintf(v1.w * rw), -lim), lim) * qw;
    op[SPATIAL4] = o;
    o.x = fminf(fmaxf(rintf(v2.x * rx), -lim), lim) * qx;
    o.y = fminf(fmaxf(rintf(v2.y * ry), -lim), lim) * qy;
    o.z = fminf(fmaxf(rintf(v2.z * rz), -lim), lim) * qz;
    o.w = fminf(fmaxf(rintf(v2.w * rw), -lim), lim) * qw;
    op[2 * SPATIAL4] = o;
    o.x = fminf(fmaxf(rintf(v3.x * rx), -lim), lim) * qx;
    o.y = fminf(fmaxf(rintf(v3.y * ry), -lim), lim) * qy;
    o.z = fminf(fmaxf(rintf(v3.z * rz), -lim), lim) * qz;
    o.w = fminf(fmaxf(rintf(v3.w * rw), -lim), lim) * qw;
    op[3 * SPATIAL4] = o;
}

extern "C" void kernel_launch(void* const* d_in, const int* in_sizes, int n_in,
                              void* d_out, int out_size, void* d_ws, size_t ws_size,
                              hipStream_t stream) {
    const float* in  = (const float*)d_in[0];
    float*       out = (float*)d_out;
    // 64Mi elements / 16 per thread = 4Mi threads = 16384 blocks of 256
    bfp_quant_kernel<<<16384, 256, 0, stream>>>(in, out);
}

// Round 4
// 419.634 us; speedup vs baseline: 1.0159x; 1.0154x over previous
//
#include <hip/hip_runtime.h>
#include <math.h>

// Problem: activations [N=8, C=64, D=32, H=64, W=64] fp32, BFP blocks of 16
// along C (stride D*H*W = 131072 elems = 512 KiB), mantissa = 7.
// R2 post-mortem: two structurally different kernels tie at dur_us=426.1/426.3;
// kernel dispatch itself is <165us (absent from top-5; harness fills dominate).
// R3 fix: HIP float4 is a class -> nontemporal builtins need a Clang
// ext_vector_type. R4 = R3's nt-hint experiment, compiling.
#define CH_STRIDE 131072   // D*H*W elements
#define SPATIAL4  32768    // CH_STRIDE / 4 (float4 groups per (n,c) plane)
#define BLK       16       // channels per BFP block

typedef float fvec4 __attribute__((ext_vector_type(4)));

__global__ __launch_bounds__(256)
void bfp_quant_kernel(const float* __restrict__ in, float* __restrict__ out) {
    const int tid   = blockIdx.x * 256 + threadIdx.x;
    const int lane  = threadIdx.x & 63;
    const int sp    = lane & 15;
    const int ch2   = lane >> 4;
    const int wid   = tid >> 6;          // global wave id, 0..65535
    const int chunk = wid & 2047;        // sp4 chunk within plane (2048 = SPATIAL4/16)
    const int nb    = wid >> 11;         // (n*4 + channel_block), 0..31
    const int sp4   = (chunk << 4) + sp;

    const long base = (long)nb * (BLK * (long)CH_STRIDE)
                    + (long)(ch2 * 4) * CH_STRIDE
                    + (long)sp4 * 4;
    const fvec4* __restrict__ ip = (const fvec4*)(in  + base);
    fvec4*       __restrict__ op = (fvec4*)(out + base);

    const fvec4 v0 = __builtin_nontemporal_load(ip);
    const fvec4 v1 = __builtin_nontemporal_load(ip + SPATIAL4);
    const fvec4 v2 = __builtin_nontemporal_load(ip + 2 * SPATIAL4);
    const fvec4 v3 = __builtin_nontemporal_load(ip + 3 * SPATIAL4);

    // per-thread max over its 4 channels, per spatial component
    float mx = fmaxf(fmaxf(fabsf(v0.x), fabsf(v1.x)), fmaxf(fabsf(v2.x), fabsf(v3.x)));
    float my = fmaxf(fmaxf(fabsf(v0.y), fabsf(v1.y)), fmaxf(fabsf(v2.y), fabsf(v3.y)));
    float mz = fmaxf(fmaxf(fabsf(v0.z), fabsf(v1.z)), fmaxf(fabsf(v2.z), fabsf(v3.z)));
    float mw = fmaxf(fmaxf(fabsf(v0.w), fabsf(v1.w)), fmaxf(fabsf(v2.w), fabsf(v3.w)));

    // butterfly across the 4 channel-quads (lanes xor 16, xor 32)
    mx = fmaxf(mx, __shfl_xor(mx, 16, 64));
    my = fmaxf(my, __shfl_xor(my, 16, 64));
    mz = fmaxf(mz, __shfl_xor(mz, 16, 64));
    mw = fmaxf(mw, __shfl_xor(mw, 16, 64));
    mx = fmaxf(mx, __shfl_xor(mx, 32, 64));
    my = fmaxf(my, __shfl_xor(my, 32, 64));
    mz = fmaxf(mz, __shfl_xor(mz, 32, 64));
    mw = fmaxf(mw, __shfl_xor(mw, 32, 64));

    // shared_exp = e-1 (frexp: max = f*2^e, f in [0.5,1)); quantum = 2^(e-7)
    int ex, ey, ez, ew;
    (void)frexpf(mx, &ex); (void)frexpf(my, &ey);
    (void)frexpf(mz, &ez); (void)frexpf(mw, &ew);
    const float qx = ldexpf(1.0f, ex - 7), rx = ldexpf(1.0f, 7 - ex);
    const float qy = ldexpf(1.0f, ey - 7), ry = ldexpf(1.0f, 7 - ey);
    const float qz = ldexpf(1.0f, ez - 7), rz = ldexpf(1.0f, 7 - ez);
    const float qw = ldexpf(1.0f, ew - 7), rw = ldexpf(1.0f, 7 - ew);
    const float lim = 127.0f;   // 2^mantissa - 1; max==0 case falls out (rint(0)=0)

    fvec4 o;
    o.x = fminf(fmaxf(rintf(v0.x * rx), -lim), lim) * qx;
    o.y = fminf(fmaxf(rintf(v0.y * ry), -lim), lim) * qy;
    o.z = fminf(fmaxf(rintf(v0.z * rz), -lim), lim) * qz;
    o.w = fminf(fmaxf(rintf(v0.w * rw), -lim), lim) * qw;
    __builtin_nontemporal_store(o, op);
    o.x = fminf(fmaxf(rintf(v1.x * rx), -lim), lim) * qx;
    o.y = fminf(fmaxf(rintf(v1.y * ry), -lim), lim) * qy;
    o.z = fminf(fmaxf(rintf(v1.z * rz), -lim), lim) * qz;
    o.w = fminf(fmaxf(rintf(v1.w * rw), -lim), lim) * qw;
    __builtin_nontemporal_store(o, op + SPATIAL4);
    o.x = fminf(fmaxf(rintf(v2.x * rx), -lim), lim) * qx;
    o.y = fminf(fmaxf(rintf(v2.y * ry), -lim), lim) * qy;
    o.z = fminf(fmaxf(rintf(v2.z * rz), -lim), lim) * qz;
    o.w = fminf(fmaxf(rintf(v2.w * rw), -lim), lim) * qw;
    __builtin_nontemporal_store(o, op + 2 * SPATIAL4);
    o.x = fminf(fmaxf(rintf(v3.x * rx), -lim), lim) * qx;
    o.y = fminf(fmaxf(rintf(v3.y * ry), -lim), lim) * qy;
    o.z = fminf(fmaxf(rintf(v3.z * rz), -lim), lim) * qz;
    o.w = fminf(fmaxf(rintf(v3.w * rw), -lim), lim) * qw;
    __builtin_nontemporal_store(o, op + 3 * SPATIAL4);
}

extern "C" void kernel_launch(void* const* d_in, const int* in_sizes, int n_in,
                              void* d_out, int out_size, void* d_ws, size_t ws_size,
                              hipStream_t stream) {
    const float* in  = (const float*)d_in[0];
    float*       out = (float*)d_out;
    // 64Mi elements / 16 per thread = 4Mi threads = 16384 blocks of 256
    bfp_quant_kernel<<<16384, 256, 0, stream>>>(in, out);
}